// Round 19
// baseline (71.010 us; speedup 1.0000x reference)
//
#include <hip/hip_runtime.h>
#include <math.h>

// Problem constants: B=2, T=1024, C=1024, NH=16, HS=64, BD=16, HORIZON=64.

typedef __attribute__((ext_vector_type(4))) float f32x4;
typedef __attribute__((ext_vector_type(8))) __bf16 bf16x8;

__device__ __forceinline__ ushort f2bf(float f) {
    union { float f; unsigned u; } v; v.f = f;
    const unsigned r = v.u + 0x7fffu + ((v.u >> 16) & 1u);   // RNE
    return (ushort)(r >> 16);
}

// Sigmoid-form gelu, trans-free, clamp-free (|z| data-bounded ~8; int-cvt
// overflow needs |z|>104). 7 full-rate VALU ops. absmax 0.023 vs 0.067 thr.
__device__ __forceinline__ float gelu_cheap(float z) {
    const int i = (int)fmaf(z, -20597949.8f, 1064866805.0f);
    const float d = 1.0f + __int_as_float(i);          // d >= ~1
    float r = __int_as_float(0x7EF311C3 - __float_as_int(d));
    r = r * fmaf(-d, r, 2.0f);                         // Newton: err ~1e-3
    return z * r;
}

// ---------------- fused QV GEMM (64x64 tile, 768 blocks) ----------------
__global__ __launch_bounds__(256) void gemm_qv_kernel(
    const ushort* __restrict__ Acat,
    const ushort* __restrict__ xb,
    const float* __restrict__ b_val,
    float* __restrict__ dprojT,
    ushort* __restrict__ valT)
{
    __shared__ ushort As[64 * 64];   // 8 KB
    __shared__ ushort Bs[64 * 64];   // 8 KB
    const int tid  = threadIdx.x;
    const int wave = tid >> 6;
    const int lane = tid & 63;
    const int rowbase = blockIdx.y * 64;
    const int colbase = blockIdx.x * 64;
    const int wr = wave >> 1;
    const int wc = wave & 1;

    f32x4 acc[2][2] = {};

    for (int k0 = 0; k0 < 1024; k0 += 64) {
        #pragma unroll
        for (int i = 0; i < 2; ++i) {
            const int p   = i * 256 + tid;                // 0..511
            const int row = p >> 3;
            const int kc  = (p & 7) ^ (row & 7);          // pre-swizzled source
            const ushort* srcA = Acat + (size_t)(rowbase + row) * 1024 + k0 + kc * 8;
            __builtin_amdgcn_global_load_lds(
                (const __attribute__((address_space(1))) void*)srcA,
                (__attribute__((address_space(3))) void*)(As + (size_t)p * 8),
                16, 0, 0);
            const ushort* srcB = xb + (size_t)(colbase + row) * 1024 + k0 + kc * 8;
            __builtin_amdgcn_global_load_lds(
                (const __attribute__((address_space(1))) void*)srcB,
                (__attribute__((address_space(3))) void*)(Bs + (size_t)p * 8),
                16, 0, 0);
        }
        __syncthreads();

        #pragma unroll
        for (int kk = 0; kk < 2; ++kk) {
            const int kb = kk * 32 + (lane >> 4) * 8;
            bf16x8 a[2], b[2];
            #pragma unroll
            for (int ni = 0; ni < 2; ++ni) {
                const int n = wc * 32 + ni * 16 + (lane & 15);
                const int off = (n * 128 + kb * 2) ^ ((n & 7) << 4);   // T2 swizzle
                b[ni] = *(const bf16x8*)((const char*)Bs + off);
            }
            #pragma unroll
            for (int mi = 0; mi < 2; ++mi) {
                const int r = wr * 32 + mi * 16 + (lane & 15);
                const int off = (r * 128 + kb * 2) ^ ((r & 7) << 4);
                a[mi] = *(const bf16x8*)((const char*)As + off);
            }
            #pragma unroll
            for (int mi = 0; mi < 2; ++mi)
                #pragma unroll
                for (int ni = 0; ni < 2; ++ni)
                    acc[mi][ni] = __builtin_amdgcn_mfma_f32_16x16x32_bf16(
                        a[mi], b[ni], acc[mi][ni], 0, 0, 0);
        }
        __syncthreads();
    }

    if (rowbase < 512) {
        #pragma unroll
        for (int mi = 0; mi < 2; ++mi)
            #pragma unroll
            for (int ni = 0; ni < 2; ++ni) {
                const int col = colbase + wc * 32 + ni * 16 + (lane & 15);
                #pragma unroll
                for (int r = 0; r < 4; ++r) {
                    const int row = rowbase + wr * 32 + mi * 16 + (lane >> 4) * 4 + r;
                    dprojT[(size_t)row * 2048 + col] = acc[mi][ni][r];
                }
            }
    } else {
        #pragma unroll
        for (int mi = 0; mi < 2; ++mi)
            #pragma unroll
            for (int ni = 0; ni < 2; ++ni) {
                const int col = colbase + wc * 32 + ni * 16 + (lane & 15);
                #pragma unroll
                for (int r = 0; r < 4; ++r) {
                    const int row = rowbase - 512 + wr * 32 + mi * 16 + (lane >> 4) * 4 + r;
                    valT[(size_t)row * 2048 + col] = f2bf(acc[mi][ni][r] + b_val[row]);
                }
            }
    }
}

// ---------------- cproj GEMM (64x64 tile, 512 blocks) --------------------
__global__ __launch_bounds__(256) void gemm_cproj_kernel(
    const ushort* __restrict__ A,    // attnb (2048,1024) bf16
    const ushort* __restrict__ Bt,   // WcT (1024,1024) bf16
    const float* __restrict__ bias,
    float* __restrict__ C)
{
    __shared__ ushort As[64 * 64];
    __shared__ ushort Bs[64 * 64];
    const int tid  = threadIdx.x;
    const int wave = tid >> 6;
    const int lane = tid & 63;
    const int rowbase = blockIdx.y * 64;
    const int colbase = blockIdx.x * 64;
    const int wr = wave >> 1;
    const int wc = wave & 1;

    f32x4 acc[2][2] = {};

    for (int k0 = 0; k0 < 1024; k0 += 64) {
        #pragma unroll
        for (int i = 0; i < 2; ++i) {
            const int p   = i * 256 + tid;                // 0..511
            const int row = p >> 3;
            const int kc  = (p & 7) ^ (row & 7);
            const ushort* srcA = A + (size_t)(rowbase + row) * 1024 + k0 + kc * 8;
            __builtin_amdgcn_global_load_lds(
                (const __attribute__((address_space(1))) void*)srcA,
                (__attribute__((address_space(3))) void*)(As + (size_t)p * 8),
                16, 0, 0);
            const ushort* srcB = Bt + (size_t)(colbase + row) * 1024 + k0 + kc * 8;
            __builtin_amdgcn_global_load_lds(
                (const __attribute__((address_space(1))) void*)srcB,
                (__attribute__((address_space(3))) void*)(Bs + (size_t)p * 8),
                16, 0, 0);
        }
        __syncthreads();

        #pragma unroll
        for (int kk = 0; kk < 2; ++kk) {
            const int kb = kk * 32 + (lane >> 4) * 8;
            bf16x8 a[2], b[2];
            #pragma unroll
            for (int ni = 0; ni < 2; ++ni) {
                const int n = wc * 32 + ni * 16 + (lane & 15);
                const int off = (n * 128 + kb * 2) ^ ((n & 7) << 4);
                b[ni] = *(const bf16x8*)((const char*)Bs + off);
            }
            #pragma unroll
            for (int mi = 0; mi < 2; ++mi) {
                const int r = wr * 32 + mi * 16 + (lane & 15);
                const int off = (r * 128 + kb * 2) ^ ((r & 7) << 4);
                a[mi] = *(const bf16x8*)((const char*)As + off);
            }
            #pragma unroll
            for (int mi = 0; mi < 2; ++mi)
                #pragma unroll
                for (int ni = 0; ni < 2; ++ni)
                    acc[mi][ni] = __builtin_amdgcn_mfma_f32_16x16x32_bf16(
                        a[mi], b[ni], acc[mi][ni], 0, 0, 0);
        }
        __syncthreads();
    }

    #pragma unroll
    for (int mi = 0; mi < 2; ++mi)
        #pragma unroll
        for (int ni = 0; ni < 2; ++ni) {
            const int col = colbase + wc * 32 + ni * 16 + (lane & 15);
            const float bvc = bias[col];
            #pragma unroll
            for (int r = 0; r < 4; ++r) {
                const int row = rowbase + wr * 32 + mi * 16 + (lane >> 4) * 4 + r;
                C[(size_t)row * 1024 + col] = acc[mi][ni][r] + bvc;
            }
        }
}

// ---------------- fused prep ----------------
__global__ __launch_bounds__(256) void prep_kernel(
    const float* __restrict__ x,
    const float* __restrict__ W_disp,
    const float* __restrict__ W_val,
    const float* __restrict__ W_cproj,
    const float* __restrict__ W_fused,
    const float* __restrict__ rel,
    const float* __restrict__ Wpos,
    ushort* __restrict__ xb,
    ushort* __restrict__ Acat,      // (1536,1024) bf16
    ushort* __restrict__ WcT,       // (1024,1024) bf16
    float* __restrict__ posf)       // (64,16)
{
    __shared__ float shmem[256 * 17 + 512];
    const int bid = blockIdx.x, tid = threadIdx.x;

    if (bid < 1024) {
        const int idx = bid * 256 + tid;
        const float4 v0 = reinterpret_cast<const float4*>(x)[idx * 2];
        const float4 v1 = reinterpret_cast<const float4*>(x)[idx * 2 + 1];
        uint4 o;
        o.x = (unsigned)f2bf(v0.x) | ((unsigned)f2bf(v0.y) << 16);
        o.y = (unsigned)f2bf(v0.z) | ((unsigned)f2bf(v0.w) << 16);
        o.z = (unsigned)f2bf(v1.x) | ((unsigned)f2bf(v1.y) << 16);
        o.w = (unsigned)f2bf(v1.z) | ((unsigned)f2bf(v1.w) << 16);
        reinterpret_cast<uint4*>(xb)[idx] = o;
    } else if (bid < 1536) {
        const int isC = bid >= 1280;
        const int b2 = bid - (isC ? 1280 : 1024);
        const float* W = isC ? W_cproj : W_val;
        ushort* Wt = isC ? WcT : (Acat + 512 * 1024);
        const int n0 = (b2 & 15) * 64;
        const int k0 = (b2 >> 4) * 64;
        float (*tile)[65] = (float (*)[65])shmem;
        #pragma unroll
        for (int i = 0; i < 4; ++i) {
            const int idx = tid + i * 256;
            const int r = idx >> 4;
            const int c = (idx & 15) << 2;
            const float4 v = *reinterpret_cast<const float4*>(
                W + (size_t)(k0 + r) * 1024 + n0 + c);
            tile[r][c] = v.x; tile[r][c+1] = v.y; tile[r][c+2] = v.z; tile[r][c+3] = v.w;
        }
        __syncthreads();
        #pragma unroll
        for (int i = 0; i < 4; ++i) {
            const int idx = tid + i * 256;
            const int n = idx >> 4;
            const int c = (idx & 15) << 2;
            ushort4 o;
            o.x = f2bf(tile[c][n]);     o.y = f2bf(tile[c + 1][n]);
            o.z = f2bf(tile[c + 2][n]); o.w = f2bf(tile[c + 3][n]);
            *reinterpret_cast<ushort4*>(Wt + (size_t)(n0 + n) * 1024 + k0 + c) = o;
        }
    } else if (bid < 1792) {
        // fold: block = (h, r-tile of 256, e-quarter of 8)
        const int b2 = bid - 1536;            // 0..255
        const int h  = b2 >> 4;               // 0..15
        const int rt = (b2 & 3) * 256;        // r-tile base
        const int eq = ((b2 >> 2) & 3) * 8;   // e-quarter base
        float (*wd_s)[17] = (float (*)[17])shmem;
        float* wfs = shmem + 256 * 17;
        {
            const float* src = W_disp + (size_t)(rt + tid) * 256 + h * 16;
            const float4 a  = *reinterpret_cast<const float4*>(src);
            const float4 c  = *reinterpret_cast<const float4*>(src + 4);
            const float4 d2 = *reinterpret_cast<const float4*>(src + 8);
            const float4 e2 = *reinterpret_cast<const float4*>(src + 12);
            wd_s[tid][0]  = a.x;  wd_s[tid][1]  = a.y;  wd_s[tid][2]  = a.z;  wd_s[tid][3]  = a.w;
            wd_s[tid][4]  = c.x;  wd_s[tid][5]  = c.y;  wd_s[tid][6]  = c.z;  wd_s[tid][7]  = c.w;
            wd_s[tid][8]  = d2.x; wd_s[tid][9]  = d2.y; wd_s[tid][10] = d2.z; wd_s[tid][11] = d2.w;
            wd_s[tid][12] = e2.x; wd_s[tid][13] = e2.y; wd_s[tid][14] = e2.z; wd_s[tid][15] = e2.w;
        }
        for (int i = tid; i < 512; i += 256) wfs[i] = W_fused[i];
        __syncthreads();
        #pragma unroll
        for (int e8 = 0; e8 < 8; ++e8) {
            const int e = eq + e8;
            float s = 0.f;
            #pragma unroll
            for (int d = 0; d < 16; ++d) s += wd_s[tid][d] * wfs[d * 32 + e];
            Acat[(size_t)(h * 32 + e) * 1024 + rt + tid] = f2bf(s);
        }
    } else {
        for (int n = tid; n < 1024; n += 256) {
            const int j = n >> 4, e = n & 15;
            float s = 0.f;
            #pragma unroll
            for (int k = 0; k < 16; ++k) s += rel[j * 16 + k] * Wpos[k * 16 + e];
            posf[n] = s;
        }
    }
}

// ---------------- weights (row-major XOR window, b128 reads, SGPR coeffs) -
// dwin[68][32]: row r <-> time t0-63+r, 128B rows, chunk-XOR slot=q^(r&7)
// (m201 pattern: 8 consecutive rows tile all 32 banks -> conflict-free b128).
// Head coefficients (Wbond/Wdmg/bfused) read with unrolled-constant indices
// from global -> scalar loads into SGPRs (no LDS, no VGPR cost).
__global__ __launch_bounds__(256) void weights_kernel(
    const float* __restrict__ dprojT, // (512, B*T=2048) chan-major
    const float* __restrict__ posf_g, // (64,16)
    const float* __restrict__ bfused, // (32)
    const float* __restrict__ Wbond,  // (16)
    const float* __restrict__ bbond,  // (1)
    const float* __restrict__ Wdmg,   // (16)
    const float* __restrict__ bdmg,   // (1)
    ushort* __restrict__ wout)        // (B*NH*T, 64) bf16
{
    __shared__ float dwin[68 * 32];   // 8.7 KB
    const int tid  = threadIdx.x;
    const int wave = tid >> 6;
    const int lane = tid & 63;
    const int bh = blockIdx.x >> 8;
    const int t0 = (blockIdx.x & 255) * 4;
    const int h  = bh & 15;
    const int b  = bh >> 4;

    // stage 32 chans x 67 rows, c-major (coalesced global); XOR-chunk LDS.
    const float* dbase = dprojT + (size_t)(h * 32) * 2048 + b * 1024;
    for (int n = tid; n < 2144; n += 256) {
        const int c = n / 67;          // 0..31
        const int r = n - c * 67;      // 0..66
        int grow = t0 - 63 + r;
        grow = grow < 0 ? 0 : grow;
        dwin[r * 32 + ((((c >> 2) ^ (r & 7)) << 2) | (c & 3))] =
            dbase[(size_t)c * 2048 + grow];
    }
    // posf[j=lane][e] + b_fused[0:16] in VGPRs
    float sbp[16];
    {
        const float4 p0 = *reinterpret_cast<const float4*>(posf_g + lane * 16);
        const float4 p1 = *reinterpret_cast<const float4*>(posf_g + lane * 16 + 4);
        const float4 p2 = *reinterpret_cast<const float4*>(posf_g + lane * 16 + 8);
        const float4 p3 = *reinterpret_cast<const float4*>(posf_g + lane * 16 + 12);
        sbp[0] = p0.x; sbp[1] = p0.y; sbp[2]  = p0.z; sbp[3]  = p0.w;
        sbp[4] = p1.x; sbp[5] = p1.y; sbp[6]  = p1.z; sbp[7]  = p1.w;
        sbp[8] = p2.x; sbp[9] = p2.y; sbp[10] = p2.z; sbp[11] = p2.w;
        sbp[12] = p3.x; sbp[13] = p3.y; sbp[14] = p3.z; sbp[15] = p3.w;
        #pragma unroll
        for (int e = 0; e < 16; ++e) sbp[e] += bfused[e];
    }
    __syncthreads();

    const int t = t0 + wave;
    const int tsrc = t + lane - 63;
    const int rw = wave + lane;       // window row for slot j=lane
    const int rt = wave + 63;         // self row (uniform broadcast)
    const int rwb = rw * 32;
    const int rtb = rt * 32;
    const int rw7 = rw & 7;
    const int rt7 = rt & 7;

    float bond = bbond[0];
    float dmg  = bdmg[0];
    #pragma unroll
    for (int q = 0; q < 4; ++q) {
        const float4 aw = *reinterpret_cast<const float4*>(&dwin[rwb + ((q ^ rw7) << 2)]);
        const float4 at = *reinterpret_cast<const float4*>(&dwin[rtb + ((q ^ rt7) << 2)]);
        const int e = q * 4;
        bond += gelu_cheap(aw.x - at.x + sbp[e + 0]) * Wbond[e + 0];
        bond += gelu_cheap(aw.y - at.y + sbp[e + 1]) * Wbond[e + 1];
        bond += gelu_cheap(aw.z - at.z + sbp[e + 2]) * Wbond[e + 2];
        bond += gelu_cheap(aw.w - at.w + sbp[e + 3]) * Wbond[e + 3];
    }
    #pragma unroll
    for (int q = 4; q < 8; ++q) {
        const float4 aw = *reinterpret_cast<const float4*>(&dwin[rwb + ((q ^ rw7) << 2)]);
        const float4 at = *reinterpret_cast<const float4*>(&dwin[rtb + ((q ^ rt7) << 2)]);
        const int e = (q - 4) * 4;
        dmg += gelu_cheap(aw.x - at.x + bfused[16 + e + 0]) * Wdmg[e + 0];
        dmg += gelu_cheap(aw.y - at.y + bfused[16 + e + 1]) * Wdmg[e + 1];
        dmg += gelu_cheap(aw.z - at.z + bfused[16 + e + 2]) * Wdmg[e + 2];
        dmg += gelu_cheap(aw.w - at.w + bfused[16 + e + 3]) * Wdmg[e + 3];
    }
    const float damage = __builtin_amdgcn_rcpf(1.0f + __expf(-dmg));
    // No-max softmax: |logit| bounded well under fp32 exp range.
    float p = __expf(bond - 10.0f * damage);
    if (tsrc < 0) p = 0.0f;

    float ssum = p;
    #pragma unroll
    for (int o = 32; o; o >>= 1) ssum += __shfl_xor(ssum, o);
    wout[(size_t)(bh * 1024 + t) * 64 + lane] = f2bf(p * __builtin_amdgcn_rcpf(ssum));
}

// ---------------- MFMA PV ----------------
__global__ __launch_bounds__(256) void pv_kernel(
    const ushort* __restrict__ valT,  // (C=1024, B*T=2048) bf16
    const ushort* __restrict__ w,     // (B*NH*T, 64) bf16
    ushort* __restrict__ attnb)       // (B*T, 1024) bf16
{
    __shared__ ushort Ps[64 * 128];   // [ti][r] swizzled, 16 KB
    __shared__ ushort Vs[64 * 128];   // [c][r]  swizzled, 16 KB
    const int tid  = threadIdx.x;
    const int wave = tid >> 6;
    const int lane = tid & 63;
    const int bh = blockIdx.x >> 4;
    const int t0 = (blockIdx.x & 15) * 64;
    const int b  = bh >> 4;
    const int h  = bh & 15;

    #pragma unroll
    for (int i = 0; i < 4; ++i) {
        const int p = i * 256 + tid;
        const int c = p >> 4, q = p & 15;
        const int kc = q ^ (c & 7);
        int tt = t0 - 64 + kc * 8;
        tt = tt < 0 ? 0 : tt;
        const ushort* src = valT + (size_t)(h * 64 + c) * 2048 + b * 1024 + tt;
        __builtin_amdgcn_global_load_lds(
            (const __attribute__((address_space(1))) void*)src,
            (__attribute__((address_space(3))) void*)(Vs + (size_t)p * 8),
            16, 0, 0);
    }
    #pragma unroll
    for (int i = 0; i < 4; ++i)
        reinterpret_cast<uint4*>(Ps)[i * 256 + tid] = uint4{0, 0, 0, 0};
    __syncthreads();
    #pragma unroll
    for (int i = 0; i < 16; ++i) {
        const int n  = i * 256 + tid;
        const int ti = n >> 6, jj = n & 63;
        const ushort wv = w[((size_t)bh * 1024 + t0 + ti) * 64 + jj];
        const int off = (ti * 256 + (ti + jj + 1) * 2) ^ ((ti & 7) << 4);
        *(ushort*)((char*)Ps + off) = wv;
    }
    __syncthreads();

    const int wr = wave >> 1;
    const int wc = wave & 1;
    f32x4 acc[2][2] = {};
    #pragma unroll
    for (int kk = 0; kk < 4; ++kk) {
        const int kb = kk * 32 + (lane >> 4) * 8;
        bf16x8 a[2], bv[2];
        #pragma unroll
        for (int ni = 0; ni < 2; ++ni) {
            const int cc = wc * 32 + ni * 16 + (lane & 15);
            const int off = (cc * 256 + kb * 2) ^ ((cc & 7) << 4);
            bv[ni] = *(const bf16x8*)((const char*)Vs + off);
        }
        #pragma unroll
        for (int mi = 0; mi < 2; ++mi) {
            const int rr = wr * 32 + mi * 16 + (lane & 15);
            const int off = (rr * 256 + kb * 2) ^ ((rr & 7) << 4);
            a[mi] = *(const bf16x8*)((const char*)Ps + off);
        }
        #pragma unroll
        for (int mi = 0; mi < 2; ++mi)
            #pragma unroll
            for (int ni = 0; ni < 2; ++ni)
                acc[mi][ni] = __builtin_amdgcn_mfma_f32_16x16x32_bf16(
                    a[mi], bv[ni], acc[mi][ni], 0, 0, 0);
    }

    #pragma unroll
    for (int mi = 0; mi < 2; ++mi)
        #pragma unroll
        for (int ni = 0; ni < 2; ++ni) {
            const int c = wc * 32 + ni * 16 + (lane & 15);
            #pragma unroll
            for (int r = 0; r < 4; ++r) {
                const int trow = t0 + wr * 32 + mi * 16 + (lane >> 4) * 4 + r;
                attnb[(size_t)(b * 1024 + trow) * 1024 + h * 64 + c] =
                    f2bf(acc[mi][ni][r]);
            }
        }
}

extern "C" void kernel_launch(void* const* d_in, const int* in_sizes, int n_in,
                              void* d_out, int out_size, void* d_ws, size_t ws_size,
                              hipStream_t stream) {
    const float* x       = (const float*)d_in[0];
    const float* W_disp  = (const float*)d_in[1];
    const float* W_val   = (const float*)d_in[3];
    const float* b_val   = (const float*)d_in[4];
    const float* rel     = (const float*)d_in[5];
    const float* W_fused = (const float*)d_in[6];
    const float* b_fused = (const float*)d_in[7];
    const float* W_pos   = (const float*)d_in[8];
    const float* W_bond  = (const float*)d_in[9];
    const float* b_bond  = (const float*)d_in[10];
    const float* W_dmg   = (const float*)d_in[11];
    const float* b_dmg   = (const float*)d_in[12];
    const float* W_cproj = (const float*)d_in[13];
    const float* b_cproj = (const float*)d_in[14];
    float* out = (float*)d_out;

    // ws: Acat 3MB | xb 4MB | WcT 2MB | dprojT fp32 4MB | valT 4MB |
    // wbuf 4MB | attnb 4MB | posf 4KB
    ushort* Acat   = (ushort*)d_ws;
    ushort* xb     = Acat + 1536 * 1024;
    ushort* WcT    = xb + 2048 * 1024;
    float*  dprojT = (float*)(WcT + 1024 * 1024);
    ushort* valT   = (ushort*)(dprojT + 512 * 2048);
    ushort* wbuf   = valT + 1024 * 2048;
    ushort* attnb  = wbuf + 32768 * 64;
    float*  posf   = (float*)(attnb + 2048 * 1024);

    dim3 blk(256);
    prep_kernel<<<dim3(1793), blk, 0, stream>>>(
        x, W_disp, W_val, W_cproj, W_fused, rel, W_pos, xb, Acat, WcT, posf);
    gemm_qv_kernel<<<dim3(2048 / 64, 1536 / 64), blk, 0, stream>>>(
        Acat, xb, b_val, dprojT, valT);
    weights_kernel<<<dim3(8192), blk, 0, stream>>>(
        dprojT, posf, b_fused, W_bond, b_bond, W_dmg, b_dmg, wbuf);
    pv_kernel<<<dim3(512), blk, 0, stream>>>(valT, wbuf, attnb);
    gemm_cproj_kernel<<<dim3(1024 / 64, 2048 / 64), blk, 0, stream>>>(
        attnb, WcT, b_cproj, out);
}

// Round 20
// 63.189 us; speedup vs baseline: 1.1238x; 1.1238x over previous
//
#include <hip/hip_runtime.h>
#include <math.h>

// Problem constants: B=2, T=1024, C=1024, NH=16, HS=64, BD=16, HORIZON=64.

typedef __attribute__((ext_vector_type(4))) float f32x4;
typedef __attribute__((ext_vector_type(8))) __bf16 bf16x8;

__device__ __forceinline__ ushort f2bf(float f) {
    union { float f; unsigned u; } v; v.f = f;
    const unsigned r = v.u + 0x7fffu + ((v.u >> 16) & 1u);   // RNE
    return (ushort)(r >> 16);
}

// Sigmoid-form gelu, trans-free, clamp-free (|z| data-bounded ~8; int-cvt
// overflow needs |z|>104). 7 full-rate VALU ops. absmax 0.023 vs 0.067 thr.
__device__ __forceinline__ float gelu_cheap(float z) {
    const int i = (int)fmaf(z, -20597949.8f, 1064866805.0f);
    const float d = 1.0f + __int_as_float(i);          // d >= ~1
    float r = __int_as_float(0x7EF311C3 - __float_as_int(d));
    r = r * fmaf(-d, r, 2.0f);                         // Newton: err ~1e-3
    return z * r;
}

// ---------------- fused QV GEMM (64x64 tile, 768 blocks) ----------------
__global__ __launch_bounds__(256) void gemm_qv_kernel(
    const ushort* __restrict__ Acat,
    const ushort* __restrict__ xb,
    const float* __restrict__ b_val,
    float* __restrict__ dprojT,
    ushort* __restrict__ valT)
{
    __shared__ ushort As[64 * 64];   // 8 KB
    __shared__ ushort Bs[64 * 64];   // 8 KB
    const int tid  = threadIdx.x;
    const int wave = tid >> 6;
    const int lane = tid & 63;
    const int rowbase = blockIdx.y * 64;
    const int colbase = blockIdx.x * 64;
    const int wr = wave >> 1;
    const int wc = wave & 1;

    f32x4 acc[2][2] = {};

    for (int k0 = 0; k0 < 1024; k0 += 64) {
        #pragma unroll
        for (int i = 0; i < 2; ++i) {
            const int p   = i * 256 + tid;                // 0..511
            const int row = p >> 3;
            const int kc  = (p & 7) ^ (row & 7);          // pre-swizzled source
            const ushort* srcA = Acat + (size_t)(rowbase + row) * 1024 + k0 + kc * 8;
            __builtin_amdgcn_global_load_lds(
                (const __attribute__((address_space(1))) void*)srcA,
                (__attribute__((address_space(3))) void*)(As + (size_t)p * 8),
                16, 0, 0);
            const ushort* srcB = xb + (size_t)(colbase + row) * 1024 + k0 + kc * 8;
            __builtin_amdgcn_global_load_lds(
                (const __attribute__((address_space(1))) void*)srcB,
                (__attribute__((address_space(3))) void*)(Bs + (size_t)p * 8),
                16, 0, 0);
        }
        __syncthreads();

        #pragma unroll
        for (int kk = 0; kk < 2; ++kk) {
            const int kb = kk * 32 + (lane >> 4) * 8;
            bf16x8 a[2], b[2];
            #pragma unroll
            for (int ni = 0; ni < 2; ++ni) {
                const int n = wc * 32 + ni * 16 + (lane & 15);
                const int off = (n * 128 + kb * 2) ^ ((n & 7) << 4);   // T2 swizzle
                b[ni] = *(const bf16x8*)((const char*)Bs + off);
            }
            #pragma unroll
            for (int mi = 0; mi < 2; ++mi) {
                const int r = wr * 32 + mi * 16 + (lane & 15);
                const int off = (r * 128 + kb * 2) ^ ((r & 7) << 4);
                a[mi] = *(const bf16x8*)((const char*)As + off);
            }
            #pragma unroll
            for (int mi = 0; mi < 2; ++mi)
                #pragma unroll
                for (int ni = 0; ni < 2; ++ni)
                    acc[mi][ni] = __builtin_amdgcn_mfma_f32_16x16x32_bf16(
                        a[mi], b[ni], acc[mi][ni], 0, 0, 0);
        }
        __syncthreads();
    }

    if (rowbase < 512) {
        #pragma unroll
        for (int mi = 0; mi < 2; ++mi)
            #pragma unroll
            for (int ni = 0; ni < 2; ++ni) {
                const int col = colbase + wc * 32 + ni * 16 + (lane & 15);
                #pragma unroll
                for (int r = 0; r < 4; ++r) {
                    const int row = rowbase + wr * 32 + mi * 16 + (lane >> 4) * 4 + r;
                    dprojT[(size_t)row * 2048 + col] = acc[mi][ni][r];
                }
            }
    } else {
        #pragma unroll
        for (int mi = 0; mi < 2; ++mi)
            #pragma unroll
            for (int ni = 0; ni < 2; ++ni) {
                const int col = colbase + wc * 32 + ni * 16 + (lane & 15);
                #pragma unroll
                for (int r = 0; r < 4; ++r) {
                    const int row = rowbase - 512 + wr * 32 + mi * 16 + (lane >> 4) * 4 + r;
                    valT[(size_t)row * 2048 + col] = f2bf(acc[mi][ni][r] + b_val[row]);
                }
            }
    }
}

// ---------------- cproj GEMM (64x64 tile, 512 blocks) --------------------
__global__ __launch_bounds__(256) void gemm_cproj_kernel(
    const ushort* __restrict__ A,    // attnb (2048,1024) bf16
    const ushort* __restrict__ Bt,   // WcT (1024,1024) bf16
    const float* __restrict__ bias,
    float* __restrict__ C)
{
    __shared__ ushort As[64 * 64];
    __shared__ ushort Bs[64 * 64];
    const int tid  = threadIdx.x;
    const int wave = tid >> 6;
    const int lane = tid & 63;
    const int rowbase = blockIdx.y * 64;
    const int colbase = blockIdx.x * 64;
    const int wr = wave >> 1;
    const int wc = wave & 1;

    f32x4 acc[2][2] = {};

    for (int k0 = 0; k0 < 1024; k0 += 64) {
        #pragma unroll
        for (int i = 0; i < 2; ++i) {
            const int p   = i * 256 + tid;                // 0..511
            const int row = p >> 3;
            const int kc  = (p & 7) ^ (row & 7);
            const ushort* srcA = A + (size_t)(rowbase + row) * 1024 + k0 + kc * 8;
            __builtin_amdgcn_global_load_lds(
                (const __attribute__((address_space(1))) void*)srcA,
                (__attribute__((address_space(3))) void*)(As + (size_t)p * 8),
                16, 0, 0);
            const ushort* srcB = Bt + (size_t)(colbase + row) * 1024 + k0 + kc * 8;
            __builtin_amdgcn_global_load_lds(
                (const __attribute__((address_space(1))) void*)srcB,
                (__attribute__((address_space(3))) void*)(Bs + (size_t)p * 8),
                16, 0, 0);
        }
        __syncthreads();

        #pragma unroll
        for (int kk = 0; kk < 2; ++kk) {
            const int kb = kk * 32 + (lane >> 4) * 8;
            bf16x8 a[2], b[2];
            #pragma unroll
            for (int ni = 0; ni < 2; ++ni) {
                const int n = wc * 32 + ni * 16 + (lane & 15);
                const int off = (n * 128 + kb * 2) ^ ((n & 7) << 4);
                b[ni] = *(const bf16x8*)((const char*)Bs + off);
            }
            #pragma unroll
            for (int mi = 0; mi < 2; ++mi) {
                const int r = wr * 32 + mi * 16 + (lane & 15);
                const int off = (r * 128 + kb * 2) ^ ((r & 7) << 4);
                a[mi] = *(const bf16x8*)((const char*)As + off);
            }
            #pragma unroll
            for (int mi = 0; mi < 2; ++mi)
                #pragma unroll
                for (int ni = 0; ni < 2; ++ni)
                    acc[mi][ni] = __builtin_amdgcn_mfma_f32_16x16x32_bf16(
                        a[mi], b[ni], acc[mi][ni], 0, 0, 0);
        }
        __syncthreads();
    }

    #pragma unroll
    for (int mi = 0; mi < 2; ++mi)
        #pragma unroll
        for (int ni = 0; ni < 2; ++ni) {
            const int col = colbase + wc * 32 + ni * 16 + (lane & 15);
            const float bvc = bias[col];
            #pragma unroll
            for (int r = 0; r < 4; ++r) {
                const int row = rowbase + wr * 32 + mi * 16 + (lane >> 4) * 4 + r;
                C[(size_t)row * 1024 + col] = acc[mi][ni][r] + bvc;
            }
        }
}

// ---------------- fused prep (R18 config) ----------------
__global__ __launch_bounds__(256) void prep_kernel(
    const float* __restrict__ x,
    const float* __restrict__ W_disp,
    const float* __restrict__ W_val,
    const float* __restrict__ W_cproj,
    const float* __restrict__ W_fused,
    const float* __restrict__ rel,
    const float* __restrict__ Wpos,
    ushort* __restrict__ xb,
    ushort* __restrict__ Acat,      // (1536,1024) bf16
    ushort* __restrict__ WcT,       // (1024,1024) bf16
    float* __restrict__ posf)       // (64,16)
{
    __shared__ float shmem[256 * 17 + 512];   // 19.5 KB
    const int bid = blockIdx.x, tid = threadIdx.x;

    if (bid < 1024) {
        // x cast: 8 floats/thread
        const int idx = bid * 256 + tid;
        const float4 v0 = reinterpret_cast<const float4*>(x)[idx * 2];
        const float4 v1 = reinterpret_cast<const float4*>(x)[idx * 2 + 1];
        uint4 o;
        o.x = (unsigned)f2bf(v0.x) | ((unsigned)f2bf(v0.y) << 16);
        o.y = (unsigned)f2bf(v0.z) | ((unsigned)f2bf(v0.w) << 16);
        o.z = (unsigned)f2bf(v1.x) | ((unsigned)f2bf(v1.y) << 16);
        o.w = (unsigned)f2bf(v1.z) | ((unsigned)f2bf(v1.w) << 16);
        reinterpret_cast<uint4*>(xb)[idx] = o;
    } else if (bid < 1536) {
        const int isC = bid >= 1280;
        const int b2 = bid - (isC ? 1280 : 1024);
        const float* W = isC ? W_cproj : W_val;
        ushort* Wt = isC ? WcT : (Acat + 512 * 1024);
        const int n0 = (b2 & 15) * 64;
        const int k0 = (b2 >> 4) * 64;
        float (*tile)[65] = (float (*)[65])shmem;
        #pragma unroll
        for (int i = 0; i < 4; ++i) {
            const int idx = tid + i * 256;
            const int r = idx >> 4;
            const int c = (idx & 15) << 2;
            const float4 v = *reinterpret_cast<const float4*>(
                W + (size_t)(k0 + r) * 1024 + n0 + c);
            tile[r][c] = v.x; tile[r][c+1] = v.y; tile[r][c+2] = v.z; tile[r][c+3] = v.w;
        }
        __syncthreads();
        #pragma unroll
        for (int i = 0; i < 4; ++i) {
            const int idx = tid + i * 256;
            const int n = idx >> 4;
            const int c = (idx & 15) << 2;
            ushort4 o;
            o.x = f2bf(tile[c][n]);     o.y = f2bf(tile[c + 1][n]);
            o.z = f2bf(tile[c + 2][n]); o.w = f2bf(tile[c + 3][n]);
            *reinterpret_cast<ushort4*>(Wt + (size_t)(n0 + n) * 1024 + k0 + c) = o;
        }
    } else if (bid < 1792) {
        // fold: block = (h, r-tile of 256, e-quarter of 8)
        const int b2 = bid - 1536;            // 0..255
        const int h  = b2 >> 4;               // 0..15
        const int rt = (b2 & 3) * 256;        // r-tile base
        const int eq = ((b2 >> 2) & 3) * 8;   // e-quarter base
        float (*wd_s)[17] = (float (*)[17])shmem;
        float* wfs = shmem + 256 * 17;
        {
            const float* src = W_disp + (size_t)(rt + tid) * 256 + h * 16;
            const float4 a  = *reinterpret_cast<const float4*>(src);
            const float4 c  = *reinterpret_cast<const float4*>(src + 4);
            const float4 d2 = *reinterpret_cast<const float4*>(src + 8);
            const float4 e2 = *reinterpret_cast<const float4*>(src + 12);
            wd_s[tid][0]  = a.x;  wd_s[tid][1]  = a.y;  wd_s[tid][2]  = a.z;  wd_s[tid][3]  = a.w;
            wd_s[tid][4]  = c.x;  wd_s[tid][5]  = c.y;  wd_s[tid][6]  = c.z;  wd_s[tid][7]  = c.w;
            wd_s[tid][8]  = d2.x; wd_s[tid][9]  = d2.y; wd_s[tid][10] = d2.z; wd_s[tid][11] = d2.w;
            wd_s[tid][12] = e2.x; wd_s[tid][13] = e2.y; wd_s[tid][14] = e2.z; wd_s[tid][15] = e2.w;
        }
        for (int i = tid; i < 512; i += 256) wfs[i] = W_fused[i];
        __syncthreads();
        #pragma unroll
        for (int e8 = 0; e8 < 8; ++e8) {
            const int e = eq + e8;
            float s = 0.f;
            #pragma unroll
            for (int d = 0; d < 16; ++d) s += wd_s[tid][d] * wfs[d * 32 + e];
            Acat[(size_t)(h * 32 + e) * 1024 + rt + tid] = f2bf(s);
        }
    } else {
        for (int n = tid; n < 1024; n += 256) {
            const int j = n >> 4, e = n & 15;
            float s = 0.f;
            #pragma unroll
            for (int k = 0; k < 16; ++k) s += rel[j * 16 + k] * Wpos[k * 16 + e];
            posf[n] = s;
        }
    }
}

// ---------------- weights (R18 config: col-major window, LDS coeffs) -----
__global__ __launch_bounds__(256) void weights_kernel(
    const float* __restrict__ dprojT, // (512, B*T=2048) chan-major
    const float* __restrict__ posf_g, // (64,16)
    const float* __restrict__ bfused, // (32)
    const float* __restrict__ Wbond,  // (16)
    const float* __restrict__ bbond,  // (1)
    const float* __restrict__ Wdmg,   // (16)
    const float* __restrict__ bdmg,   // (1)
    ushort* __restrict__ wout)        // (B*NH*T, 64) bf16
{
    __shared__ float dwin[32][68];    // [chan][row]: rows t0-63 .. t0+3
    __shared__ float sbd[16];
    __shared__ float wbd[16];
    __shared__ float wdm[16];
    const int tid  = threadIdx.x;
    const int wave = tid >> 6;
    const int lane = tid & 63;
    const int bh = blockIdx.x >> 8;
    const int t0 = (blockIdx.x & 255) * 4;
    const int h  = bh & 15;
    const int b  = bh >> 4;

    if (tid < 16) {
        sbd[tid] = bfused[16 + tid];
        wbd[tid] = Wbond[tid];
        wdm[tid] = Wdmg[tid];
    }
    const float* dbase = dprojT + (size_t)(h * 32) * 2048 + b * 1024;
    {
        const int r = tid & 63;
        int grow = t0 - 63 + r;
        grow = grow < 0 ? 0 : grow;
        #pragma unroll
        for (int i = 0; i < 8; ++i) {
            const int c = (tid >> 6) + i * 4;
            dwin[c][r] = dbase[(size_t)c * 2048 + grow];
        }
    }
    if (tid < 128) {
        const int c = tid >> 2;
        const int rs = tid & 3;
        if (rs < 3) {
            const int r = 64 + rs;
            int grow = t0 - 63 + r;   // >= 1 always; max 1023. no clamp needed
            dwin[c][r] = dbase[(size_t)c * 2048 + grow];
        }
    }
    float sbp[16];
    {
        const float4 p0 = *reinterpret_cast<const float4*>(posf_g + lane * 16);
        const float4 p1 = *reinterpret_cast<const float4*>(posf_g + lane * 16 + 4);
        const float4 p2 = *reinterpret_cast<const float4*>(posf_g + lane * 16 + 8);
        const float4 p3 = *reinterpret_cast<const float4*>(posf_g + lane * 16 + 12);
        sbp[0] = p0.x; sbp[1] = p0.y; sbp[2]  = p0.z; sbp[3]  = p0.w;
        sbp[4] = p1.x; sbp[5] = p1.y; sbp[6]  = p1.z; sbp[7]  = p1.w;
        sbp[8] = p2.x; sbp[9] = p2.y; sbp[10] = p2.z; sbp[11] = p2.w;
        sbp[12] = p3.x; sbp[13] = p3.y; sbp[14] = p3.z; sbp[15] = p3.w;
        #pragma unroll
        for (int e = 0; e < 16; ++e) sbp[e] += bfused[e];
    }
    __syncthreads();

    const int t = t0 + wave;
    const int tsrc = t + lane - 63;
    const int rw = wave + lane;
    const int rt = wave + 63;

    float bond = bbond[0];
    float dmg  = bdmg[0];
    #pragma unroll
    for (int e = 0; e < 16; ++e) {
        bond += gelu_cheap(dwin[e][rw] - dwin[e][rt] + sbp[e]) * wbd[e];
        dmg  += gelu_cheap(dwin[16 + e][rw] - dwin[16 + e][rt] + sbd[e]) * wdm[e];
    }
    const float damage = __builtin_amdgcn_rcpf(1.0f + __expf(-dmg));
    // No-max softmax: |logit| bounded well under fp32 exp range.
    float p = __expf(bond - 10.0f * damage);
    if (tsrc < 0) p = 0.0f;

    float ssum = p;
    #pragma unroll
    for (int o = 32; o; o >>= 1) ssum += __shfl_xor(ssum, o);
    wout[(size_t)(bh * 1024 + t) * 64 + lane] = f2bf(p * __builtin_amdgcn_rcpf(ssum));
}

// ---------------- MFMA PV ----------------
__global__ __launch_bounds__(256) void pv_kernel(
    const ushort* __restrict__ valT,  // (C=1024, B*T=2048) bf16
    const ushort* __restrict__ w,     // (B*NH*T, 64) bf16
    ushort* __restrict__ attnb)       // (B*T, 1024) bf16
{
    __shared__ ushort Ps[64 * 128];   // [ti][r] swizzled, 16 KB
    __shared__ ushort Vs[64 * 128];   // [c][r]  swizzled, 16 KB
    const int tid  = threadIdx.x;
    const int wave = tid >> 6;
    const int lane = tid & 63;
    const int bh = blockIdx.x >> 4;
    const int t0 = (blockIdx.x & 15) * 64;
    const int b  = bh >> 4;
    const int h  = bh & 15;

    #pragma unroll
    for (int i = 0; i < 4; ++i) {
        const int p = i * 256 + tid;
        const int c = p >> 4, q = p & 15;
        const int kc = q ^ (c & 7);
        int tt = t0 - 64 + kc * 8;
        tt = tt < 0 ? 0 : tt;
        const ushort* src = valT + (size_t)(h * 64 + c) * 2048 + b * 1024 + tt;
        __builtin_amdgcn_global_load_lds(
            (const __attribute__((address_space(1))) void*)src,
            (__attribute__((address_space(3))) void*)(Vs + (size_t)p * 8),
            16, 0, 0);
    }
    #pragma unroll
    for (int i = 0; i < 4; ++i)
        reinterpret_cast<uint4*>(Ps)[i * 256 + tid] = uint4{0, 0, 0, 0};
    __syncthreads();
    #pragma unroll
    for (int i = 0; i < 16; ++i) {
        const int n  = i * 256 + tid;
        const int ti = n >> 6, jj = n & 63;
        const ushort wv = w[((size_t)bh * 1024 + t0 + ti) * 64 + jj];
        const int off = (ti * 256 + (ti + jj + 1) * 2) ^ ((ti & 7) << 4);
        *(ushort*)((char*)Ps + off) = wv;
    }
    __syncthreads();

    const int wr = wave >> 1;
    const int wc = wave & 1;
    f32x4 acc[2][2] = {};
    #pragma unroll
    for (int kk = 0; kk < 4; ++kk) {
        const int kb = kk * 32 + (lane >> 4) * 8;
        bf16x8 a[2], bv[2];
        #pragma unroll
        for (int ni = 0; ni < 2; ++ni) {
            const int cc = wc * 32 + ni * 16 + (lane & 15);
            const int off = (cc * 256 + kb * 2) ^ ((cc & 7) << 4);
            bv[ni] = *(const bf16x8*)((const char*)Vs + off);
        }
        #pragma unroll
        for (int mi = 0; mi < 2; ++mi) {
            const int rr = wr * 32 + mi * 16 + (lane & 15);
            const int off = (rr * 256 + kb * 2) ^ ((rr & 7) << 4);
            a[mi] = *(const bf16x8*)((const char*)Ps + off);
        }
        #pragma unroll
        for (int mi = 0; mi < 2; ++mi)
            #pragma unroll
            for (int ni = 0; ni < 2; ++ni)
                acc[mi][ni] = __builtin_amdgcn_mfma_f32_16x16x32_bf16(
                    a[mi], bv[ni], acc[mi][ni], 0, 0, 0);
    }

    #pragma unroll
    for (int mi = 0; mi < 2; ++mi)
        #pragma unroll
        for (int ni = 0; ni < 2; ++ni) {
            const int c = wc * 32 + ni * 16 + (lane & 15);
            #pragma unroll
            for (int r = 0; r < 4; ++r) {
                const int trow = t0 + wr * 32 + mi * 16 + (lane >> 4) * 4 + r;
                attnb[(size_t)(b * 1024 + trow) * 1024 + h * 64 + c] =
                    f2bf(acc[mi][ni][r]);
            }
        }
}

extern "C" void kernel_launch(void* const* d_in, const int* in_sizes, int n_in,
                              void* d_out, int out_size, void* d_ws, size_t ws_size,
                              hipStream_t stream) {
    const float* x       = (const float*)d_in[0];
    const float* W_disp  = (const float*)d_in[1];
    const float* W_val   = (const float*)d_in[3];
    const float* b_val   = (const float*)d_in[4];
    const float* rel     = (const float*)d_in[5];
    const float* W_fused = (const float*)d_in[6];
    const float* b_fused = (const float*)d_in[7];
    const float* W_pos   = (const float*)d_in[8];
    const float* W_bond  = (const float*)d_in[9];
    const float* b_bond  = (const float*)d_in[10];
    const float* W_dmg   = (const float*)d_in[11];
    const float* b_dmg   = (const float*)d_in[12];
    const float* W_cproj = (const float*)d_in[13];
    const float* b_cproj = (const float*)d_in[14];
    float* out = (float*)d_out;

    // ws: Acat 3MB | xb 4MB | WcT 2MB | dprojT fp32 4MB | valT 4MB |
    // wbuf 4MB | attnb 4MB | posf 4KB
    ushort* Acat   = (ushort*)d_ws;
    ushort* xb     = Acat + 1536 * 1024;
    ushort* WcT    = xb + 2048 * 1024;
    float*  dprojT = (float*)(WcT + 1024 * 1024);
    ushort* valT   = (ushort*)(dprojT + 512 * 2048);
    ushort* wbuf   = valT + 1024 * 2048;
    ushort* attnb  = wbuf + 32768 * 64;
    float*  posf   = (float*)(attnb + 2048 * 1024);

    dim3 blk(256);
    prep_kernel<<<dim3(1793), blk, 0, stream>>>(
        x, W_disp, W_val, W_cproj, W_fused, rel, W_pos, xb, Acat, WcT, posf);
    gemm_qv_kernel<<<dim3(2048 / 64, 1536 / 64), blk, 0, stream>>>(
        Acat, xb, b_val, dprojT, valT);
    weights_kernel<<<dim3(8192), blk, 0, stream>>>(
        dprojT, posf, b_fused, W_bond, b_bond, W_dmg, b_dmg, wbuf);
    pv_kernel<<<dim3(512), blk, 0, stream>>>(valT, wbuf, attnb);
    gemm_cproj_kernel<<<dim3(1024 / 64, 2048 / 64), blk, 0, stream>>>(
        attnb, WcT, b_cproj, out);
}